// Round 18
// baseline (139.979 us; speedup 1.0000x reference)
//
#include <hip/hip_runtime.h>

typedef float f32x4  __attribute__((ext_vector_type(4)));
typedef short s16x8  __attribute__((ext_vector_type(8)));
typedef short s16x4  __attribute__((ext_vector_type(4)));
typedef unsigned short u16x8 __attribute__((ext_vector_type(8)));
typedef unsigned int   u32x2 __attribute__((ext_vector_type(2)));
typedef unsigned int   u32x4 __attribute__((ext_vector_type(4)));

#define DM   1024
#define LSEQ 2048
#define NH   16
#define HD   64
#define MTOT 4096   // B * LSEQ
#define RS   3072   // QKV row stride

__device__ __forceinline__ unsigned short f2bf(float f) {
  union { float f; unsigned int u; } v; v.f = f;
  unsigned int r = (v.u + 0x7fffu + ((v.u >> 16) & 1u)) >> 16;
  return (unsigned short)r;
}

// v_cvt_pk_bf16_f32: dst = {lo: bf16(lo), hi: bf16(hi)} (RNE)
__device__ __forceinline__ unsigned cvtpk(float lo, float hi) {
  unsigned r;
  asm volatile("v_cvt_pk_bf16_f32 %0, %1, %2" : "=v"(r) : "v"(lo), "v"(hi));
  return r;
}
__device__ __forceinline__ s16x8 cvt8(float4 a, float4 b) {
  u32x4 o = {cvtpk(a.x, a.y), cvtpk(a.z, a.w), cvtpk(b.x, b.y), cvtpk(b.z, b.w)};
  return __builtin_bit_cast(s16x8, o);
}

// ---------------- 4x W [K][N] fp32 -> Wt [N][K] bf16 (z = which W) ----------
__global__ __launch_bounds__(256) void wtrans4(const float* __restrict__ W0,
                                               const float* __restrict__ W1,
                                               const float* __restrict__ W2,
                                               const float* __restrict__ W3,
                                               unsigned short* __restrict__ Wt) {
  __shared__ __align__(16) unsigned short t[64][72];
  const int z = blockIdx.z;
  const float* W = (z == 0) ? W0 : (z == 1) ? W1 : (z == 2) ? W2 : W3;
  unsigned short* dst = Wt + (size_t)z * DM * DM;
  const int n0 = blockIdx.x * 64, k0 = blockIdx.y * 64;
  const int r = threadIdx.x >> 4, c4 = (threadIdx.x & 15) * 4;
#pragma unroll
  for (int rr = r; rr < 64; rr += 16) {
    float4 v = *(const float4*)&W[(long)(k0 + rr) * DM + n0 + c4];
    ushort4 u;
    u.x = f2bf(v.x); u.y = f2bf(v.y); u.z = f2bf(v.z); u.w = f2bf(v.w);
    *(ushort4*)&t[rr][c4] = u;
  }
  __syncthreads();
#pragma unroll
  for (int rr = r; rr < 64; rr += 16) {
    ushort4 u;
    u.x = t[c4 + 0][rr]; u.y = t[c4 + 1][rr];
    u.z = t[c4 + 2][rr]; u.w = t[c4 + 3][rr];
    *(ushort4*)&dst[(long)(n0 + rr) * DM + k0 + c4] = u;
  }
}

// ---------------- GEMM (reg-staged, padded LDS, prefetch-before-MFMA) -------
// QKV_MODE=1: A is fp32 x (converted during staging); Q cols pre-scaled by
// 0.125*log2e; V cols (>=2048) written TRANSPOSED into VT[bh][d][seq].
template <int QKV_MODE>
__global__ __launch_bounds__(256) void gemm_bt(
    const void* __restrict__ Aptr, const unsigned short* __restrict__ Bt,
    const float* __restrict__ bias0, const float* __restrict__ bias1,
    const float* __restrict__ bias2, void* __restrict__ Cout,
    unsigned short* __restrict__ VT, int N, int K) {
  __shared__ __align__(16) unsigned short As[128][72];
  __shared__ __align__(16) unsigned short Bs[128][72];
  const int tid = threadIdx.x;
  const int lane = tid & 63, w = tid >> 6;
  const int r16 = lane & 15, g = lane >> 4;
  const int m0 = blockIdx.y * 128, n0 = blockIdx.x * 128;
  const int wm = (w >> 1) * 64, wn = (w & 1) * 64;
  const int srow = tid >> 2, scol = (tid & 3) * 8;
  const float* Agf = (const float*)Aptr + (long)(m0 + srow) * K + scol;
  const unsigned short* Agh = (const unsigned short*)Aptr + (long)(m0 + srow) * K + scol;
  const unsigned short* Bg = Bt + (long)(n0 + srow) * K + scol;
  f32x4 acc[4][4] = {};
  float4 fa0, fa1, fa2, fa3, fa4, fa5, fa6, fa7;
  s16x8 a0, a1, a2, a3, b0, b1, b2, b3;

#define GLOAD_AB(koff)                                                        \
  {                                                                           \
    if constexpr (QKV_MODE) {                                                 \
      const float* p = Agf + (koff);                                          \
      fa0 = *(const float4*)p;        fa1 = *(const float4*)(p + 4);          \
      fa2 = *(const float4*)(p + 32); fa3 = *(const float4*)(p + 36);         \
      const float* q = p + 64L * K;                                           \
      fa4 = *(const float4*)q;        fa5 = *(const float4*)(q + 4);          \
      fa6 = *(const float4*)(q + 32); fa7 = *(const float4*)(q + 36);         \
    } else {                                                                  \
      const unsigned short* p = Agh + (koff);                                 \
      a0 = *(const s16x8*)p;             a1 = *(const s16x8*)(p + 32);        \
      a2 = *(const s16x8*)(p + 64L * K); a3 = *(const s16x8*)(p + 64L * K + 32); \
    }                                                                         \
    const unsigned short* pb = Bg + (koff);                                   \
    b0 = *(const s16x8*)pb;             b1 = *(const s16x8*)(pb + 32);        \
    b2 = *(const s16x8*)(pb + 64L * K); b3 = *(const s16x8*)(pb + 64L * K + 32); \
  }

  GLOAD_AB(0);
  for (int kt = 0; kt < K; kt += 64) {
    __syncthreads();
    if constexpr (QKV_MODE) {
      *(s16x8*)&As[srow][scol]           = cvt8(fa0, fa1);
      *(s16x8*)&As[srow][scol + 32]      = cvt8(fa2, fa3);
      *(s16x8*)&As[srow + 64][scol]      = cvt8(fa4, fa5);
      *(s16x8*)&As[srow + 64][scol + 32] = cvt8(fa6, fa7);
    } else {
      *(s16x8*)&As[srow][scol]           = a0;
      *(s16x8*)&As[srow][scol + 32]      = a1;
      *(s16x8*)&As[srow + 64][scol]      = a2;
      *(s16x8*)&As[srow + 64][scol + 32] = a3;
    }
    *(s16x8*)&Bs[srow][scol]           = b0;
    *(s16x8*)&Bs[srow][scol + 32]      = b1;
    *(s16x8*)&Bs[srow + 64][scol]      = b2;
    *(s16x8*)&Bs[srow + 64][scol + 32] = b3;
    __syncthreads();
    if (kt + 64 < K) GLOAD_AB(kt + 64);
#pragma unroll
    for (int kk = 0; kk < 64; kk += 32) {
      s16x8 af[4], bf[4];
#pragma unroll
      for (int i = 0; i < 4; i++) af[i] = *(const s16x8*)&As[wm + i * 16 + r16][kk + g * 8];
#pragma unroll
      for (int j = 0; j < 4; j++) bf[j] = *(const s16x8*)&Bs[wn + j * 16 + r16][kk + g * 8];
#pragma unroll
      for (int i = 0; i < 4; i++)
#pragma unroll
        for (int j = 0; j < 4; j++)
          acc[i][j] = __builtin_amdgcn_mfma_f32_16x16x32_bf16(af[i], bf[j], acc[i][j], 0, 0, 0);
    }
  }
#undef GLOAD_AB

  if (QKV_MODE && n0 >= 2048) {
#pragma unroll
    for (int i = 0; i < 4; i++) {
      const int row0 = m0 + wm + i * 16 + g * 4;
      const int b = row0 >> 11, seq = row0 & 2047;
#pragma unroll
      for (int j = 0; j < 4; j++) {
        const int cv = n0 + wn + j * 16 + r16 - 2048;
        const float bb = bias2[cv];
        const int bh = b * NH + (cv >> 6), d = cv & 63;
        ushort4 u;
        u.x = f2bf(acc[i][j][0] + bb);
        u.y = f2bf(acc[i][j][1] + bb);
        u.z = f2bf(acc[i][j][2] + bb);
        u.w = f2bf(acc[i][j][3] + bb);
        *(ushort4*)(VT + ((size_t)bh * HD + d) * LSEQ + seq) = u;
      }
    }
    return;
  }
#pragma unroll
  for (int i = 0; i < 4; i++) {
#pragma unroll
    for (int j = 0; j < 4; j++) {
      const int row = m0 + wm + i * 16 + g * 4;
      const int col = n0 + wn + j * 16 + r16;
      float bb, sc = 1.0f;
      if constexpr (QKV_MODE) {
        bb = (col < 1024) ? bias0[col] : bias1[col - 1024];
        if (col < 1024) sc = 0.18033688011112042f;  // 0.125 * log2(e)
      } else {
        bb = bias0[col];
      }
#pragma unroll
      for (int r = 0; r < 4; r++) {
        float v = (acc[i][j][r] + bb) * sc;
        if constexpr (QKV_MODE)
          ((unsigned short*)Cout)[(long)(row + r) * N + col] = f2bf(v);
        else
          ((float*)Cout)[(long)(row + r) * N + col] = v;
      }
    }
  }
}

// ---------------- flash attention: split-K + rotated pipeline ---------------
// attn9 math verbatim; schedule rotated so QK^T(t+1) [MFMA] overlaps
// softmax(t) [VALU]. 3-deep LDS ring keeps ONE barrier per tile:
// write(t+2) targets the buffer whose readers finished before the previous
// barrier. LDS 114 KB (free: kernel runs at 1 block/CU regardless).
__global__ __launch_bounds__(512) void attn11(const unsigned short* __restrict__ QKV,
                                              const unsigned short* __restrict__ VT,
                                              unsigned short* __restrict__ O) {
  __shared__ __align__(16) unsigned short Ks[2][3][64][76];  // [half][ring]
  __shared__ __align__(16) unsigned short Vs[2][3][64][76];
  __shared__ float Lsum[4][32];
  const int tid = threadIdx.x;
  const int lane = tid & 63, w = tid >> 6;     // w in 0..7
  const int wq = w & 3;                        // q-row group
  const int hb = tid >> 8;                     // key half
  const int r16 = lane & 15, g = lane >> 4;
  const int qb = blockIdx.x, bh = blockIdx.y;
  const int b = bh >> 4, h = bh & 15;

  const unsigned short* QgA =
      QKV + (size_t)(b * LSEQ + qb * 128 + wq * 32 + r16) * RS + h * HD;
  const unsigned short* QgB = QgA + 16 * RS;
  const s16x8 qa0 = *(const s16x8*)&QgA[g * 8];
  const s16x8 qa1 = *(const s16x8*)&QgA[32 + g * 8];
  const s16x8 qb0 = *(const s16x8*)&QgB[g * 8];
  const s16x8 qb1 = *(const s16x8*)&QgB[32 + g * 8];

  const unsigned short* Kb =
      QKV + (size_t)(b * LSEQ + hb * 1024) * RS + DM + h * HD;       // K[seq][d]
  const unsigned short* Vb =
      VT + (size_t)(bh * HD) * LSEQ + hb * 1024;                     // VT[d][seq-half]
  const int t256 = tid & 255;
  const int srow = t256 >> 2, scol = (t256 & 3) * 8;

  f32x4 oA[4] = {}, oB[4] = {};
  float psA[4] = {0.f, 0.f, 0.f, 0.f};
  float psB[4] = {0.f, 0.f, 0.f, 0.f};

#define LOAD_TILE(tt)                                                     \
  {                                                                       \
    const size_t ko = (size_t)((tt) * 64 + srow) * RS + scol;             \
    const size_t vo = (size_t)srow * LSEQ + (tt) * 64 + scol;             \
    k0 = *(const s16x8*)&Kb[ko];                                          \
    k1 = *(const s16x8*)&Kb[ko + 32];                                     \
    v0 = *(const s16x8*)&Vb[vo];                                          \
    v1 = *(const s16x8*)&Vb[vo + 32];                                     \
  }
#define WRITE_TILE(buf)                                                   \
  {                                                                       \
    *(s16x8*)&Ks[hb][buf][srow][scol]      = k0;                          \
    *(s16x8*)&Ks[hb][buf][srow][scol + 32] = k1;                          \
    *(s16x8*)&Vs[hb][buf][srow][scol]      = v0;                          \
    *(s16x8*)&Vs[hb][buf][srow][scol + 32] = v1;                          \
  }
#define QK_TILE(buf, sA, sB)                                              \
  _Pragma("unroll")                                                       \
  for (int kc = 0; kc < 4; kc++) {                                        \
    s16x8 kb0 = *(const s16x8*)&Ks[hb][buf][kc * 16 + r16][g * 8];        \
    s16x8 kb1 = *(const s16x8*)&Ks[hb][buf][kc * 16 + r16][32 + g * 8];   \
    f32x4 zA = {}, zB = {};                                               \
    zA = __builtin_amdgcn_mfma_f32_16x16x32_bf16(kb0, qa0, zA, 0, 0, 0);  \
    sA[kc] = __builtin_amdgcn_mfma_f32_16x16x32_bf16(kb1, qa1, zA, 0, 0, 0); \
    zB = __builtin_amdgcn_mfma_f32_16x16x32_bf16(kb0, qb0, zB, 0, 0, 0);  \
    sB[kc] = __builtin_amdgcn_mfma_f32_16x16x32_bf16(kb1, qb1, zB, 0, 0, 0); \
  }

  s16x8 k0, k1, v0, v1;
  f32x4 spA[4], spB[4], snA[4], snB[4];

  // prologue: stage tiles 0,1; QK(0)
  LOAD_TILE(0);
  WRITE_TILE(0);
  LOAD_TILE(1);            // in-flight during barrier
  __syncthreads();         // tile 0 visible
  QK_TILE(0, spA, spB);
  WRITE_TILE(1);
  LOAD_TILE(2);
  __syncthreads();         // tile 1 visible

  int cur = 0, nxt = 1, wrt = 2;   // ring indices: t%3, (t+1)%3, (t+2)%3
  for (int tt = 0; tt < 16; ++tt) {
    // 1. QK^T(t+1) [MFMA] -- independent, overlaps softmax(t) below
    if (tt + 1 < 16) QK_TILE(nxt, snA, snB);

    // 2. softmax(t) [VALU] on scores from previous iteration
    s16x4 paA[4], paB[4];
#pragma unroll
    for (int kc = 0; kc < 4; kc++) {
      float a0f = exp2f(spA[kc][0]);
      float a1f = exp2f(spA[kc][1]);
      float a2f = exp2f(spA[kc][2]);
      float a3f = exp2f(spA[kc][3]);
      psA[0] += a0f; psA[1] += a1f; psA[2] += a2f; psA[3] += a3f;
      u32x2 pkA = {cvtpk(a0f, a1f), cvtpk(a2f, a3f)};
      paA[kc] = __builtin_bit_cast(s16x4, pkA);
      float b0f = exp2f(spB[kc][0]);
      float b1f = exp2f(spB[kc][1]);
      float b2f = exp2f(spB[kc][2]);
      float b3f = exp2f(spB[kc][3]);
      psB[0] += b0f; psB[1] += b1f; psB[2] += b2f; psB[3] += b3f;
      u32x2 pkB = {cvtpk(b0f, b1f), cvtpk(b2f, b3f)};
      paB[kc] = __builtin_bit_cast(s16x4, pkB);
    }

    // 3. PV(t)
#pragma unroll
    for (int kc = 0; kc < 4; kc++)
#pragma unroll
      for (int dc = 0; dc < 4; dc++) {
        s16x4 vb = *(const s16x4*)&Vs[hb][cur][dc * 16 + r16][kc * 16 + 4 * g];
        oA[dc] = __builtin_amdgcn_mfma_f32_16x16x16bf16_1k(paA[kc], vb, oA[dc], 0, 0, 0);
        oB[dc] = __builtin_amdgcn_mfma_f32_16x16x16bf16_1k(paB[kc], vb, oB[dc], 0, 0, 0);
      }

    // 4. stage tile t+2 (regs loaded last iteration); 5. issue loads(t+3)
    if (tt + 2 < 16) {
      WRITE_TILE(wrt);
      if (tt + 3 < 16) LOAD_TILE(tt + 3);
    }

    // 6. one barrier per tile; 7. rotate score regs + ring
    if (tt + 1 < 16) {
      __syncthreads();
#pragma unroll
      for (int kc = 0; kc < 4; kc++) { spA[kc] = snA[kc]; spB[kc] = snB[kc]; }
      int t = cur; cur = nxt; nxt = wrt; wrt = t;
    }
  }
#undef LOAD_TILE
#undef WRITE_TILE
#undef QK_TILE

  // ---- combine halves through the (now dead) K/V LDS ----
  __syncthreads();
  float (*xo)[33] = reinterpret_cast<float(*)[33]>(&Ks[0][0][0][0]);  // 33.8KB
  float (*xs)[9]  = reinterpret_cast<float(*)[9]>(&Vs[0][0][0][0]);   // 9.2KB
  if (w >= 4) {
    const int l = tid & 255;
#pragma unroll
    for (int dc = 0; dc < 4; dc++) {
      *(f32x4*)&xo[l][4 * dc]      = oA[dc];
      *(f32x4*)&xo[l][16 + 4 * dc] = oB[dc];
    }
#pragma unroll
    for (int r = 0; r < 4; r++) { xs[l][r] = psA[r]; xs[l][4 + r] = psB[r]; }
  }
  __syncthreads();
  float totA = 0.f, totB = 0.f;
  if (w < 4) {
    const int l = tid;
#pragma unroll
    for (int dc = 0; dc < 4; dc++) {
      oA[dc] += *(const f32x4*)&xo[l][4 * dc];
      oB[dc] += *(const f32x4*)&xo[l][16 + 4 * dc];
    }
#pragma unroll
    for (int r = 0; r < 4; r++) { psA[r] += xs[l][r]; psB[r] += xs[l][4 + r]; }
    totA = psA[0] + psA[1] + psA[2] + psA[3];
    totA += __shfl_xor(totA, 16);
    totA += __shfl_xor(totA, 32);
    totB = psB[0] + psB[1] + psB[2] + psB[3];
    totB += __shfl_xor(totB, 16);
    totB += __shfl_xor(totB, 32);
    if (g == 0) {
      Lsum[wq][r16]      = totA;
      Lsum[wq][16 + r16] = totB;
    }
  }
  __syncthreads();
  if (w < 4) {
    const float4 svA = *(const float4*)&Lsum[wq][4 * g];
    const float4 svB = *(const float4*)&Lsum[wq][16 + 4 * g];
    unsigned short* Og = O + (size_t)(b * LSEQ + qb * 128 + wq * 32) * DM + h * HD;
#pragma unroll
    for (int r = 0; r < 4; r++) {
      const float invA = 1.0f / ((const float*)&svA)[r];
      const float invB = 1.0f / ((const float*)&svB)[r];
#pragma unroll
      for (int dc = 0; dc < 4; dc++) {
        Og[(size_t)(g * 4 + r) * DM + dc * 16 + r16]      = f2bf(oA[dc][r] * invA);
        Og[(size_t)(16 + g * 4 + r) * DM + dc * 16 + r16] = f2bf(oB[dc][r] * invB);
      }
    }
  }
}

extern "C" void kernel_launch(void* const* d_in, const int* in_sizes, int n_in,
                              void* d_out, int out_size, void* d_ws, size_t ws_size,
                              hipStream_t stream) {
  const float* x  = (const float*)d_in[0];
  const float* Wq = (const float*)d_in[1];
  const float* bq = (const float*)d_in[2];
  const float* Wk = (const float*)d_in[3];
  const float* bk = (const float*)d_in[4];
  const float* Wv = (const float*)d_in[5];
  const float* bv = (const float*)d_in[6];
  const float* Wo = (const float*)d_in[7];
  const float* bo = (const float*)d_in[8];

  unsigned short* VTb  = (unsigned short*)d_ws;            // 4M bf16 (VT, by gemm<1>)
  unsigned short* Wcat = VTb + (size_t)MTOT * DM;          // 3M bf16 (Wq^T|Wk^T|Wv^T)
  unsigned short* Wot  = Wcat + (size_t)3 * DM * DM;       // 1M bf16
  unsigned short* QKVb = Wot + (size_t)DM * DM;            // 12M bf16 (V third unused)
  unsigned short* Ob   = QKVb + (size_t)MTOT * 3 * DM;     // 4M bf16

  wtrans4<<<dim3(16, 16, 4), 256, 0, stream>>>(Wq, Wk, Wv, Wo, Wcat);

  gemm_bt<1><<<dim3(3 * DM / 128, MTOT / 128), 256, 0, stream>>>(
      (const void*)x, Wcat, bq, bk, bv, (void*)QKVb, VTb, 3 * DM, DM);
  attn11<<<dim3(LSEQ / 128, 2 * NH), 512, 0, stream>>>(QKVb, VTb, Ob);
  gemm_bt<0><<<dim3(DM / 128, MTOT / 128), 256, 0, stream>>>(
      (const void*)Ob, Wot, bo, nullptr, nullptr, d_out, nullptr, DM, DM);
}

// Round 19
// 136.807 us; speedup vs baseline: 1.0232x; 1.0232x over previous
//
#include <hip/hip_runtime.h>

typedef float f32x4  __attribute__((ext_vector_type(4)));
typedef short s16x8  __attribute__((ext_vector_type(8)));
typedef short s16x4  __attribute__((ext_vector_type(4)));
typedef unsigned short u16x8 __attribute__((ext_vector_type(8)));
typedef unsigned int   u32x2 __attribute__((ext_vector_type(2)));
typedef unsigned int   u32x4 __attribute__((ext_vector_type(4)));

#define DM   1024
#define LSEQ 2048
#define NH   16
#define HD   64
#define MTOT 4096   // B * LSEQ
#define RS   3072   // QKV row stride

__device__ __forceinline__ unsigned short f2bf(float f) {
  union { float f; unsigned int u; } v; v.f = f;
  unsigned int r = (v.u + 0x7fffu + ((v.u >> 16) & 1u)) >> 16;
  return (unsigned short)r;
}

// v_cvt_pk_bf16_f32: dst = {lo: bf16(lo), hi: bf16(hi)} (RNE)
__device__ __forceinline__ unsigned cvtpk(float lo, float hi) {
  unsigned r;
  asm volatile("v_cvt_pk_bf16_f32 %0, %1, %2" : "=v"(r) : "v"(lo), "v"(hi));
  return r;
}
__device__ __forceinline__ s16x8 cvt8(float4 a, float4 b) {
  u32x4 o = {cvtpk(a.x, a.y), cvtpk(a.z, a.w), cvtpk(b.x, b.y), cvtpk(b.z, b.w)};
  return __builtin_bit_cast(s16x8, o);
}

// ---------------- 4x W [K][N] fp32 -> Wt [N][K] bf16 (z = which W) ----------
__global__ __launch_bounds__(256) void wtrans4(const float* __restrict__ W0,
                                               const float* __restrict__ W1,
                                               const float* __restrict__ W2,
                                               const float* __restrict__ W3,
                                               unsigned short* __restrict__ Wt) {
  __shared__ __align__(16) unsigned short t[64][72];
  const int z = blockIdx.z;
  const float* W = (z == 0) ? W0 : (z == 1) ? W1 : (z == 2) ? W2 : W3;
  unsigned short* dst = Wt + (size_t)z * DM * DM;
  const int n0 = blockIdx.x * 64, k0 = blockIdx.y * 64;
  const int r = threadIdx.x >> 4, c4 = (threadIdx.x & 15) * 4;
#pragma unroll
  for (int rr = r; rr < 64; rr += 16) {
    float4 v = *(const float4*)&W[(long)(k0 + rr) * DM + n0 + c4];
    ushort4 u;
    u.x = f2bf(v.x); u.y = f2bf(v.y); u.z = f2bf(v.z); u.w = f2bf(v.w);
    *(ushort4*)&t[rr][c4] = u;
  }
  __syncthreads();
#pragma unroll
  for (int rr = r; rr < 64; rr += 16) {
    ushort4 u;
    u.x = t[c4 + 0][rr]; u.y = t[c4 + 1][rr];
    u.z = t[c4 + 2][rr]; u.w = t[c4 + 3][rr];
    *(ushort4*)&dst[(long)(n0 + rr) * DM + k0 + c4] = u;
  }
}

// ---------------- GEMM (reg-staged, padded LDS, prefetch-before-MFMA) -------
// QKV_MODE=1: A is fp32 x (converted during staging); Q cols pre-scaled by
// 0.125*log2e; V cols (>=2048) written TRANSPOSED into VT[bh][d][seq]
// (vtrans fused) and NOT written to the QKV buffer.
template <int QKV_MODE>
__global__ __launch_bounds__(256) void gemm_bt(
    const void* __restrict__ Aptr, const unsigned short* __restrict__ Bt,
    const float* __restrict__ bias0, const float* __restrict__ bias1,
    const float* __restrict__ bias2, void* __restrict__ Cout,
    unsigned short* __restrict__ VT, int N, int K) {
  __shared__ __align__(16) unsigned short As[128][72];
  __shared__ __align__(16) unsigned short Bs[128][72];
  const int tid = threadIdx.x;
  const int lane = tid & 63, w = tid >> 6;
  const int r16 = lane & 15, g = lane >> 4;
  const int m0 = blockIdx.y * 128, n0 = blockIdx.x * 128;
  const int wm = (w >> 1) * 64, wn = (w & 1) * 64;
  const int srow = tid >> 2, scol = (tid & 3) * 8;
  const float* Agf = (const float*)Aptr + (long)(m0 + srow) * K + scol;
  const unsigned short* Agh = (const unsigned short*)Aptr + (long)(m0 + srow) * K + scol;
  const unsigned short* Bg = Bt + (long)(n0 + srow) * K + scol;
  f32x4 acc[4][4] = {};
  float4 fa0, fa1, fa2, fa3, fa4, fa5, fa6, fa7;
  s16x8 a0, a1, a2, a3, b0, b1, b2, b3;

#define GLOAD_AB(koff)                                                        \
  {                                                                           \
    if constexpr (QKV_MODE) {                                                 \
      const float* p = Agf + (koff);                                          \
      fa0 = *(const float4*)p;        fa1 = *(const float4*)(p + 4);          \
      fa2 = *(const float4*)(p + 32); fa3 = *(const float4*)(p + 36);         \
      const float* q = p + 64L * K;                                           \
      fa4 = *(const float4*)q;        fa5 = *(const float4*)(q + 4);          \
      fa6 = *(const float4*)(q + 32); fa7 = *(const float4*)(q + 36);         \
    } else {                                                                  \
      const unsigned short* p = Agh + (koff);                                 \
      a0 = *(const s16x8*)p;             a1 = *(const s16x8*)(p + 32);        \
      a2 = *(const s16x8*)(p + 64L * K); a3 = *(const s16x8*)(p + 64L * K + 32); \
    }                                                                         \
    const unsigned short* pb = Bg + (koff);                                   \
    b0 = *(const s16x8*)pb;             b1 = *(const s16x8*)(pb + 32);        \
    b2 = *(const s16x8*)(pb + 64L * K); b3 = *(const s16x8*)(pb + 64L * K + 32); \
  }

  GLOAD_AB(0);
  for (int kt = 0; kt < K; kt += 64) {
    __syncthreads();
    if constexpr (QKV_MODE) {
      *(s16x8*)&As[srow][scol]           = cvt8(fa0, fa1);
      *(s16x8*)&As[srow][scol + 32]      = cvt8(fa2, fa3);
      *(s16x8*)&As[srow + 64][scol]      = cvt8(fa4, fa5);
      *(s16x8*)&As[srow + 64][scol + 32] = cvt8(fa6, fa7);
    } else {
      *(s16x8*)&As[srow][scol]           = a0;
      *(s16x8*)&As[srow][scol + 32]      = a1;
      *(s16x8*)&As[srow + 64][scol]      = a2;
      *(s16x8*)&As[srow + 64][scol + 32] = a3;
    }
    *(s16x8*)&Bs[srow][scol]           = b0;
    *(s16x8*)&Bs[srow][scol + 32]      = b1;
    *(s16x8*)&Bs[srow + 64][scol]      = b2;
    *(s16x8*)&Bs[srow + 64][scol + 32] = b3;
    __syncthreads();
    if (kt + 64 < K) GLOAD_AB(kt + 64);
#pragma unroll
    for (int kk = 0; kk < 64; kk += 32) {
      s16x8 af[4], bf[4];
#pragma unroll
      for (int i = 0; i < 4; i++) af[i] = *(const s16x8*)&As[wm + i * 16 + r16][kk + g * 8];
#pragma unroll
      for (int j = 0; j < 4; j++) bf[j] = *(const s16x8*)&Bs[wn + j * 16 + r16][kk + g * 8];
#pragma unroll
      for (int i = 0; i < 4; i++)
#pragma unroll
        for (int j = 0; j < 4; j++)
          acc[i][j] = __builtin_amdgcn_mfma_f32_16x16x32_bf16(af[i], bf[j], acc[i][j], 0, 0, 0);
    }
  }
#undef GLOAD_AB

  if (QKV_MODE && n0 >= 2048) {
    // V block: write transposed into VT[bh][d][seq] (seq contiguous in r)
#pragma unroll
    for (int i = 0; i < 4; i++) {
      const int row0 = m0 + wm + i * 16 + g * 4;      // rows row0..row0+3
      const int b = row0 >> 11, seq = row0 & 2047;
#pragma unroll
      for (int j = 0; j < 4; j++) {
        const int cv = n0 + wn + j * 16 + r16 - 2048; // h*64 + d
        const float bb = bias2[cv];
        const int bh = b * NH + (cv >> 6), d = cv & 63;
        ushort4 u;
        u.x = f2bf(acc[i][j][0] + bb);
        u.y = f2bf(acc[i][j][1] + bb);
        u.z = f2bf(acc[i][j][2] + bb);
        u.w = f2bf(acc[i][j][3] + bb);
        *(ushort4*)(VT + ((size_t)bh * HD + d) * LSEQ + seq) = u;
      }
    }
    return;
  }
#pragma unroll
  for (int i = 0; i < 4; i++) {
#pragma unroll
    for (int j = 0; j < 4; j++) {
      const int row = m0 + wm + i * 16 + g * 4;
      const int col = n0 + wn + j * 16 + r16;
      float bb, sc = 1.0f;
      if constexpr (QKV_MODE) {
        bb = (col < 1024) ? bias0[col] : bias1[col - 1024];
        if (col < 1024) sc = 0.18033688011112042f;  // 0.125 * log2(e): exp2-domain softmax
      } else {
        bb = bias0[col];
      }
#pragma unroll
      for (int r = 0; r < 4; r++) {
        float v = (acc[i][j][r] + bb) * sc;
        if constexpr (QKV_MODE)
          ((unsigned short*)Cout)[(long)(row + r) * N + col] = f2bf(v);
        else
          ((float*)Cout)[(long)(row + r) * N + col] = v;
      }
    }
  }
}

// ---------------- flash attention: in-block key-split, 8 waves --------------
// grid: (2*NH bh, LSEQ/128 qb) -- round-15 configuration (best measured:
// 136.6 us total). 512 threads; waves 0-3: keys [0,1024); waves 4-7: keys
// [1024,2048) for the SAME 128 q-rows. Max-free softmax => halves combine by
// pure summation. No setprio (r16: null on lockstep structure).
__global__ __launch_bounds__(512) void attn9(const unsigned short* __restrict__ QKV,
                                             const unsigned short* __restrict__ VT,
                                             unsigned short* __restrict__ O) {
  __shared__ __align__(16) unsigned short Ks[2][2][64][76];  // [half][dbuf]
  __shared__ __align__(16) unsigned short Vs[2][2][64][76];
  __shared__ float Lsum[4][32];
  const int tid = threadIdx.x;
  const int lane = tid & 63, w = tid >> 6;     // w in 0..7
  const int wq = w & 3;                        // q-row group
  const int hb = tid >> 8;                     // key half
  const int r16 = lane & 15, g = lane >> 4;
  const int bh = blockIdx.x, qb = blockIdx.y;  // bh-major (round-15 ordering)
  const int b = bh >> 4, h = bh & 15;

  const unsigned short* QgA =
      QKV + (size_t)(b * LSEQ + qb * 128 + wq * 32 + r16) * RS + h * HD;
  const unsigned short* QgB = QgA + 16 * RS;
  const s16x8 qa0 = *(const s16x8*)&QgA[g * 8];
  const s16x8 qa1 = *(const s16x8*)&QgA[32 + g * 8];
  const s16x8 qb0 = *(const s16x8*)&QgB[g * 8];
  const s16x8 qb1 = *(const s16x8*)&QgB[32 + g * 8];

  const unsigned short* Kb =
      QKV + (size_t)(b * LSEQ + hb * 1024) * RS + DM + h * HD;       // K[seq][d]
  const unsigned short* Vb =
      VT + (size_t)(bh * HD) * LSEQ + hb * 1024;                     // VT[d][seq-half]
  const int t256 = tid & 255;
  const int srow = t256 >> 2, scol = (t256 & 3) * 8;

  f32x4 oA[4] = {}, oB[4] = {};
  float psA[4] = {0.f, 0.f, 0.f, 0.f};
  float psB[4] = {0.f, 0.f, 0.f, 0.f};

  s16x8 k0 = *(const s16x8*)&Kb[(size_t)srow * RS + scol];
  s16x8 k1 = *(const s16x8*)&Kb[(size_t)srow * RS + scol + 32];
  s16x8 v0 = *(const s16x8*)&Vb[(size_t)srow * LSEQ + scol];
  s16x8 v1 = *(const s16x8*)&Vb[(size_t)srow * LSEQ + scol + 32];
  *(s16x8*)&Ks[hb][0][srow][scol]      = k0;
  *(s16x8*)&Ks[hb][0][srow][scol + 32] = k1;
  *(s16x8*)&Vs[hb][0][srow][scol]      = v0;
  *(s16x8*)&Vs[hb][0][srow][scol + 32] = v1;
  __syncthreads();

  for (int tt = 0; tt < 16; ++tt) {
    const int cur = tt & 1;
    if (tt + 1 < 16) {
      const size_t ko = (size_t)((tt + 1) * 64 + srow) * RS + scol;
      const size_t vo = (size_t)srow * LSEQ + (tt + 1) * 64 + scol;
      k0 = *(const s16x8*)&Kb[ko];
      k1 = *(const s16x8*)&Kb[ko + 32];
      v0 = *(const s16x8*)&Vb[vo];
      v1 = *(const s16x8*)&Vb[vo + 32];
    }

    f32x4 sA[4], sB[4];
#pragma unroll
    for (int kc = 0; kc < 4; kc++) {
      s16x8 kb0 = *(const s16x8*)&Ks[hb][cur][kc * 16 + r16][g * 8];
      s16x8 kb1 = *(const s16x8*)&Ks[hb][cur][kc * 16 + r16][32 + g * 8];
      f32x4 zA = {}, zB = {};
      zA = __builtin_amdgcn_mfma_f32_16x16x32_bf16(kb0, qa0, zA, 0, 0, 0);
      sA[kc] = __builtin_amdgcn_mfma_f32_16x16x32_bf16(kb1, qa1, zA, 0, 0, 0);
      zB = __builtin_amdgcn_mfma_f32_16x16x32_bf16(kb0, qb0, zB, 0, 0, 0);
      sB[kc] = __builtin_amdgcn_mfma_f32_16x16x32_bf16(kb1, qb1, zB, 0, 0, 0);
    }

    s16x4 paA[4], paB[4];
#pragma unroll
    for (int kc = 0; kc < 4; kc++) {
      float a0f = exp2f(sA[kc][0]);
      float a1f = exp2f(sA[kc][1]);
      float a2f = exp2f(sA[kc][2]);
      float a3f = exp2f(sA[kc][3]);
      psA[0] += a0f; psA[1] += a1f; psA[2] += a2f; psA[3] += a3f;
      u32x2 pkA = {cvtpk(a0f, a1f), cvtpk(a2f, a3f)};
      paA[kc] = __builtin_bit_cast(s16x4, pkA);
      float b0f = exp2f(sB[kc][0]);
      float b1f = exp2f(sB[kc][1]);
      float b2f = exp2f(sB[kc][2]);
      float b3f = exp2f(sB[kc][3]);
      psB[0] += b0f; psB[1] += b1f; psB[2] += b2f; psB[3] += b3f;
      u32x2 pkB = {cvtpk(b0f, b1f), cvtpk(b2f, b3f)};
      paB[kc] = __builtin_bit_cast(s16x4, pkB);
    }

#pragma unroll
    for (int kc = 0; kc < 4; kc++)
#pragma unroll
      for (int dc = 0; dc < 4; dc++) {
        s16x4 vb = *(const s16x4*)&Vs[hb][cur][dc * 16 + r16][kc * 16 + 4 * g];
        oA[dc] = __builtin_amdgcn_mfma_f32_16x16x16bf16_1k(paA[kc], vb, oA[dc], 0, 0, 0);
        oB[dc] = __builtin_amdgcn_mfma_f32_16x16x16bf16_1k(paB[kc], vb, oB[dc], 0, 0, 0);
      }

    if (tt + 1 < 16) {
      *(s16x8*)&Ks[hb][cur ^ 1][srow][scol]      = k0;
      *(s16x8*)&Ks[hb][cur ^ 1][srow][scol + 32] = k1;
      *(s16x8*)&Vs[hb][cur ^ 1][srow][scol]      = v0;
      *(s16x8*)&Vs[hb][cur ^ 1][srow][scol + 32] = v1;
      __syncthreads();
    }
  }

  // ---- combine halves through the (now dead) K/V LDS ----
  __syncthreads();
  float (*xo)[33] = reinterpret_cast<float(*)[33]>(&Ks[0][0][0][0]);  // 33.8KB
  float (*xs)[9]  = reinterpret_cast<float(*)[9]>(&Vs[0][0][0][0]);   // 9.2KB
  if (w >= 4) {
    const int l = tid & 255;
#pragma unroll
    for (int dc = 0; dc < 4; dc++) {
      *(f32x4*)&xo[l][4 * dc]      = oA[dc];
      *(f32x4*)&xo[l][16 + 4 * dc] = oB[dc];
    }
#pragma unroll
    for (int r = 0; r < 4; r++) { xs[l][r] = psA[r]; xs[l][4 + r] = psB[r]; }
  }
  __syncthreads();
  float totA = 0.f, totB = 0.f;
  if (w < 4) {
    const int l = tid;
#pragma unroll
    for (int dc = 0; dc < 4; dc++) {
      oA[dc] += *(const f32x4*)&xo[l][4 * dc];
      oB[dc] += *(const f32x4*)&xo[l][16 + 4 * dc];
    }
#pragma unroll
    for (int r = 0; r < 4; r++) { psA[r] += xs[l][r]; psB[r] += xs[l][4 + r]; }
    totA = psA[0] + psA[1] + psA[2] + psA[3];
    totA += __shfl_xor(totA, 16);
    totA += __shfl_xor(totA, 32);
    totB = psB[0] + psB[1] + psB[2] + psB[3];
    totB += __shfl_xor(totB, 16);
    totB += __shfl_xor(totB, 32);
    if (g == 0) {
      Lsum[wq][r16]      = totA;
      Lsum[wq][16 + r16] = totB;
    }
  }
  __syncthreads();
  if (w < 4) {
    const float4 svA = *(const float4*)&Lsum[wq][4 * g];
    const float4 svB = *(const float4*)&Lsum[wq][16 + 4 * g];
    unsigned short* Og = O + (size_t)(b * LSEQ + qb * 128 + wq * 32) * DM + h * HD;
#pragma unroll
    for (int r = 0; r < 4; r++) {
      const float invA = 1.0f / ((const float*)&svA)[r];
      const float invB = 1.0f / ((const float*)&svB)[r];
#pragma unroll
      for (int dc = 0; dc < 4; dc++) {
        Og[(size_t)(g * 4 + r) * DM + dc * 16 + r16]      = f2bf(oA[dc][r] * invA);
        Og[(size_t)(16 + g * 4 + r) * DM + dc * 16 + r16] = f2bf(oB[dc][r] * invB);
      }
    }
  }
}

extern "C" void kernel_launch(void* const* d_in, const int* in_sizes, int n_in,
                              void* d_out, int out_size, void* d_ws, size_t ws_size,
                              hipStream_t stream) {
  const float* x  = (const float*)d_in[0];
  const float* Wq = (const float*)d_in[1];
  const float* bq = (const float*)d_in[2];
  const float* Wk = (const float*)d_in[3];
  const float* bk = (const float*)d_in[4];
  const float* Wv = (const float*)d_in[5];
  const float* bv = (const float*)d_in[6];
  const float* Wo = (const float*)d_in[7];
  const float* bo = (const float*)d_in[8];

  unsigned short* VTb  = (unsigned short*)d_ws;            // 4M bf16 (VT, by gemm<1>)
  unsigned short* Wcat = VTb + (size_t)MTOT * DM;          // 3M bf16 (Wq^T|Wk^T|Wv^T)
  unsigned short* Wot  = Wcat + (size_t)3 * DM * DM;       // 1M bf16
  unsigned short* QKVb = Wot + (size_t)DM * DM;            // 12M bf16 (V third unused)
  unsigned short* Ob   = QKVb + (size_t)MTOT * 3 * DM;     // 4M bf16

  wtrans4<<<dim3(16, 16, 4), 256, 0, stream>>>(Wq, Wk, Wv, Wo, Wcat);

  gemm_bt<1><<<dim3(3 * DM / 128, MTOT / 128), 256, 0, stream>>>(
      (const void*)x, Wcat, bq, bk, bv, (void*)QKVb, VTb, 3 * DM, DM);
  attn9<<<dim3(2 * NH, LSEQ / 128), 512, 0, stream>>>(QKVb, VTb, Ob);
  gemm_bt<0><<<dim3(DM / 128, MTOT / 128), 256, 0, stream>>>(
      (const void*)Ob, Wot, bo, nullptr, nullptr, d_out, nullptr, DM, DM);
}